// Round 15
// baseline (796.962 us; speedup 1.0000x reference)
//
#include <hip/hip_runtime.h>
#include <hip/hip_bf16.h>

#define NN 100000
#define NE 640000
#define DD 128
#define NG 64
#define NL 3
#define BN_EPS 1e-5f

typedef unsigned short u16;
typedef unsigned int u32;
typedef __attribute__((ext_vector_type(8))) short short8;
typedef __attribute__((ext_vector_type(4))) float f32x4;

__device__ __forceinline__ void atomAddG(float* p, float v) { unsafeAtomicAdd(p, v); }

__device__ __forceinline__ float bf_lo(u32 u) { return __uint_as_float(u << 16); }
__device__ __forceinline__ float bf_hi(u32 u) { return __uint_as_float(u & 0xffff0000u); }
__device__ __forceinline__ float bfs(short s) { return __uint_as_float(((u32)(u16)s) << 16); }
__device__ __forceinline__ u16 bfb(float f) {
    __hip_bfloat16 b = __float2bfloat16(f);
    return *(u16*)&b;
}
__device__ __forceinline__ u32 pk(float a, float b) {
    return (u32)bfb(a) | ((u32)bfb(b) << 16);
}

// stat block layout: st[0..127] = column sums, st[128..255] = column sumsq
__device__ __forceinline__ void bn_coef(const float* __restrict__ st,
                                        const float* __restrict__ g,
                                        const float* __restrict__ be,
                                        int c, float& s, float& f) {
    float m = st[c] * (1.0f / NN);
    float v = st[128 + c] * (1.0f / NN) - m * m;
    s = g[c] * rsqrtf(v + BN_EPS);
    f = be[c] - m * s;
}

// ---------------- CSR build ----------------
__global__ void k_degI(const int* __restrict__ dst, int* __restrict__ degI) {
    int e = blockIdx.x * 256 + threadIdx.x;
    if (e < NE) atomicAdd(&degI[dst[e]], 1);
}

// scan1 + dinv fused
__global__ void k_scan1(const int* __restrict__ degI, int* __restrict__ offs, int* __restrict__ bsum,
                        float* __restrict__ dinv) {
    __shared__ int ls[256];
    int t = threadIdx.x;
    int i = blockIdx.x * 256 + t;
    int v = (i < NN) ? degI[i] : 0;
    if (i < NN) dinv[i] = v > 0 ? rsqrtf((float)v) : 0.f;
    ls[t] = v;
    __syncthreads();
    for (int off = 1; off < 256; off <<= 1) {
        int u = (t >= off) ? ls[t - off] : 0;
        __syncthreads();
        ls[t] += u;
        __syncthreads();
    }
    if (i < NN) offs[i] = ls[t] - v;
    if (t == 255) bsum[blockIdx.x] = ls[255];
}

__global__ void k_scan2(int* __restrict__ bsum, int nb) {
    __shared__ int ls[512];
    int t = threadIdx.x;
    int v = (t < nb) ? bsum[t] : 0;
    ls[t] = v;
    __syncthreads();
    for (int off = 1; off < 512; off <<= 1) {
        int u = (t >= off) ? ls[t - off] : 0;
        __syncthreads();
        ls[t] += u;
        __syncthreads();
    }
    if (t < nb) bsum[t] = ls[t] - v;
}

__global__ void k_scan3(int* __restrict__ offs, const int* __restrict__ bsum) {
    int i = blockIdx.x * 256 + threadIdx.x;
    if (i < NN) offs[i] += bsum[blockIdx.x];
    if (i == 0) offs[NN] = NE;
}

__global__ void k_place(const int* __restrict__ src, const int* __restrict__ dst,
                        const int* __restrict__ offs, int* __restrict__ cur,
                        u32* __restrict__ eIdx) {
    int e = blockIdx.x * 256 + threadIdx.x;
    if (e < NE) {
        int d = dst[e];
        int pos = offs[d] + atomicAdd(&cur[d], 1);
        eIdx[pos] = (u32)src[e];
    }
}

// W [k][n] f32 -> Wt [n][k] bf16 ; matrices: 0=enc_W1 1=enc_W2 2..4=conv_W
__global__ void k_prepW(const float* __restrict__ W1, const float* __restrict__ W2,
                        const float* __restrict__ CW, u16* __restrict__ wtb) {
    int m = blockIdx.x >> 3;
    const float* src = (m == 0) ? W1 : (m == 1) ? W2 : CW + (size_t)(m - 2) * 16384;
    u16* dst = wtb + (size_t)m * 16384;
    int base = (blockIdx.x & 7) * 2048 + threadIdx.x;
#pragma unroll
    for (int i = 0; i < 8; ++i) {
        int idx = base + i * 256;
        int k = idx >> 7, n = idx & 127;
        dst[n * 128 + k] = bfb(src[idx]);
    }
}

// ---------------- MFMA GEMM [NN,128] @ Wt[128][128] ----------------
// MODE 0: conv. A = hb (bf16). Out: t1 u32 row-major, rows PRE-SCALED by dinv[row].
// MODE 1: encoder1. A = x (f32, convert on load). Out: bf16 row-major + stats into statOut.
// MODE 2: encoder2. A = tb16 bf16; BN+ReLU coeffs computed INLINE from bnSt/bnG/bnBe;
//         +bias. Out: hb bf16 + h f32.
template <int MODE>
__global__ __launch_bounds__(256) void k_mm(
    const void* __restrict__ Av, const u16* __restrict__ Wt,
    const float* __restrict__ bias,
    const float* __restrict__ bnSt, const float* __restrict__ bnG, const float* __restrict__ bnBe,
    const float* __restrict__ dinv,
    u16* __restrict__ Cb, float* __restrict__ Cf,
    float* __restrict__ statOut)
{
    __shared__ float lC[64 * 128];
    __shared__ float sBN[256];
    int tid = threadIdx.x;
    int l = tid & 63, w = tid >> 6;
    int lr = l & 15, lg = l >> 4;
    int wcol = (w & 1) * 64, wrow = (w >> 1) * 32;

    if (MODE == 2) {
        if (tid < 128) {
            float s, f;
            bn_coef(bnSt, bnG, bnBe, tid, s, f);
            sBN[tid] = s;
            sBN[128 + tid] = f;
        }
        __syncthreads();
    }

    short8 Bf[4][4];
#pragma unroll
    for (int ct = 0; ct < 4; ++ct)
#pragma unroll
        for (int ks = 0; ks < 4; ++ks)
            Bf[ct][ks] = *(const short8*)(Wt + (size_t)(wcol + ct * 16 + lr) * 128 + ks * 32 + lg * 8);

    f32x4 acc[2][4];
#pragma unroll
    for (int rg = 0; rg < 2; ++rg)
#pragma unroll
        for (int ct = 0; ct < 4; ++ct)
            acc[rg][ct] = (f32x4){0.f, 0.f, 0.f, 0.f};

    int rbase = blockIdx.x * 64 + wrow;
#pragma unroll
    for (int rg = 0; rg < 2; ++rg) {
        int row = rbase + rg * 16 + lr;
        row = min(row, NN - 1);
        short8 Af[4];
        if (MODE == 1) {
            const float* af = (const float*)Av + (size_t)row * 128 + lg * 8;
#pragma unroll
            for (int ks = 0; ks < 4; ++ks) {
                float4 v0 = *(const float4*)(af + ks * 32);
                float4 v1 = *(const float4*)(af + ks * 32 + 4);
                short8 o;
                o[0] = (short)bfb(v0.x); o[1] = (short)bfb(v0.y);
                o[2] = (short)bfb(v0.z); o[3] = (short)bfb(v0.w);
                o[4] = (short)bfb(v1.x); o[5] = (short)bfb(v1.y);
                o[6] = (short)bfb(v1.z); o[7] = (short)bfb(v1.w);
                Af[ks] = o;
            }
        } else {
            const u16* ap = (const u16*)Av + (size_t)row * 128 + lg * 8;
#pragma unroll
            for (int ks = 0; ks < 4; ++ks) Af[ks] = *(const short8*)(ap + ks * 32);
            if (MODE == 2) {
#pragma unroll
                for (int ks = 0; ks < 4; ++ks) {
                    int cb = ks * 32 + lg * 8;
                    float4 s0 = *(const float4*)(sBN + cb), s1 = *(const float4*)(sBN + cb + 4);
                    float4 f0 = *(const float4*)(sBN + 128 + cb), f1 = *(const float4*)(sBN + 128 + cb + 4);
                    short8 a = Af[ks], o;
                    o[0] = (short)bfb(fmaxf(0.f, bfs(a[0]) * s0.x + f0.x));
                    o[1] = (short)bfb(fmaxf(0.f, bfs(a[1]) * s0.y + f0.y));
                    o[2] = (short)bfb(fmaxf(0.f, bfs(a[2]) * s0.z + f0.z));
                    o[3] = (short)bfb(fmaxf(0.f, bfs(a[3]) * s0.w + f0.w));
                    o[4] = (short)bfb(fmaxf(0.f, bfs(a[4]) * s1.x + f1.x));
                    o[5] = (short)bfb(fmaxf(0.f, bfs(a[5]) * s1.y + f1.y));
                    o[6] = (short)bfb(fmaxf(0.f, bfs(a[6]) * s1.z + f1.z));
                    o[7] = (short)bfb(fmaxf(0.f, bfs(a[7]) * s1.w + f1.w));
                    Af[ks] = o;
                }
            }
        }
#pragma unroll
        for (int ks = 0; ks < 4; ++ks)
#pragma unroll
            for (int ct = 0; ct < 4; ++ct)
                acc[rg][ct] = __builtin_amdgcn_mfma_f32_16x16x32_bf16(Af[ks], Bf[ct][ks], acc[rg][ct], 0, 0, 0);
    }

    if (MODE == 2) {
#pragma unroll
        for (int ct = 0; ct < 4; ++ct) {
            float bc = bias[wcol + ct * 16 + lr];
#pragma unroll
            for (int rg = 0; rg < 2; ++rg)
#pragma unroll
                for (int j = 0; j < 4; ++j) acc[rg][ct][j] += bc;
        }
    }

#pragma unroll
    for (int rg = 0; rg < 2; ++rg)
#pragma unroll
        for (int ct = 0; ct < 4; ++ct)
#pragma unroll
            for (int j = 0; j < 4; ++j)
                lC[(wrow + rg * 16 + lg * 4 + j) * 128 + wcol + ct * 16 + lr] = acc[rg][ct][j];
    __syncthreads();

    float cs[4] = {0.f, 0.f, 0.f, 0.f}, cq[4] = {0.f, 0.f, 0.f, 0.f};
#pragma unroll
    for (int i = 0; i < 8; ++i) {
        int eidx = i * 1024 + tid * 4;
        int lrow = eidx >> 7;
        int col = eidx & 127;
        int grow = blockIdx.x * 64 + lrow;
        if (grow < NN) {
            float4 v = *(float4*)(lC + eidx);
            if (MODE == 0) {
                float dd = dinv[grow];
                v.x *= dd; v.y *= dd; v.z *= dd; v.w *= dd;
                u32* Cs = (u32*)Cb;
                *(uint2*)(Cs + (size_t)grow * 64 + (col >> 1)) =
                    make_uint2(pk(v.x, v.y), pk(v.z, v.w));
            } else {
                uint2 o = make_uint2(pk(v.x, v.y), pk(v.z, v.w));
                *(uint2*)(Cb + (size_t)grow * 128 + col) = o;
                if (MODE == 2) *(float4*)(Cf + (size_t)grow * 128 + col) = v;
                if (MODE == 1) {
                    cs[0] += v.x; cs[1] += v.y; cs[2] += v.z; cs[3] += v.w;
                    cq[0] += v.x * v.x; cq[1] += v.y * v.y; cq[2] += v.z * v.z; cq[3] += v.w * v.w;
                }
            }
        }
    }

    if (MODE == 1) {
        __syncthreads();
        int g = tid >> 5, c0 = (tid & 31) * 4;
#pragma unroll
        for (int cc = 0; cc < 4; ++cc) {
            lC[g * 128 + c0 + cc] = cs[cc];
            lC[1024 + g * 128 + c0 + cc] = cq[cc];
        }
        __syncthreads();
        if (tid < 128) {
            float s = 0.f, q = 0.f;
#pragma unroll
            for (int g2 = 0; g2 < 8; ++g2) { s += lC[g2 * 128 + tid]; q += lC[1024 + g2 * 128 + tid]; }
            atomAddG(&statOut[tid], s);
            atomAddG(&statOut[128 + tid], q);
        }
    }
}

// ---------------- CSR pull aggregation: 2 dsts x chunk-8 per wave ----------
// Grid sized so each wave does EXACTLY one dst-pair (25000 waves = NN/2 pairs):
// fine granularity keeps CUs backfilled instead of draining on degree imbalance.
__global__ __launch_bounds__(256) void k_agg(
    const u32* __restrict__ hwb,          // [NN][64] u32 (bf16x2), pre-scaled rows
    const u32* __restrict__ eIdx, const int* __restrict__ offs,
    const float* __restrict__ dinv,
    u32* __restrict__ aggb, float* __restrict__ statOut)
{
    int tid = threadIdx.x;
    int lane = tid & 63;
    int wav = tid >> 6;
    int gw = blockIdx.x * 4 + wav;
    int nw = gridDim.x * 4;
    float sx0 = 0.f, sx1 = 0.f, sq0 = 0.f, sq1 = 0.f;

    for (int d0 = gw * 2; d0 < NN; d0 += nw * 2) {
        int a0 = offs[d0], a1 = offs[d0 + 1], a2 = offs[d0 + 2];
        int len0 = a1 - a0, len1 = a2 - a1;
        int m0 = max(len0 - 1, 0), m1 = max(len1 - 1, 0);
        float x0 = 0.f, y0 = 0.f, x1 = 0.f, y1 = 0.f;
        int mx = max(len0, len1);
        for (int jb = 0; jb < mx; jb += 8) {
            u32 i0[8], i1[8];
#pragma unroll
            for (int q = 0; q < 8; ++q) {
                i0[q] = eIdx[min(a0 + min(jb + q, m0), NE - 1)];
                i1[q] = eIdx[min(a1 + min(jb + q, m1), NE - 1)];
            }
            u32 u0[8], u1[8];
#pragma unroll
            for (int q = 0; q < 8; ++q) {
                u0[q] = hwb[(size_t)i0[q] * 64 + lane];
                u1[q] = hwb[(size_t)i1[q] * 64 + lane];
            }
#pragma unroll
            for (int q = 0; q < 8; ++q) {
                bool v0 = (jb + q) < len0, v1 = (jb + q) < len1;
                x0 += v0 ? bf_lo(u0[q]) : 0.f;
                y0 += v0 ? bf_hi(u0[q]) : 0.f;
                x1 += v1 ? bf_lo(u1[q]) : 0.f;
                y1 += v1 ? bf_hi(u1[q]) : 0.f;
            }
        }
        float dd0 = dinv[d0], dd1 = dinv[d0 + 1];
        x0 *= dd0; y0 *= dd0; x1 *= dd1; y1 *= dd1;
        aggb[(size_t)d0 * 64 + lane] = pk(x0, y0);
        aggb[(size_t)(d0 + 1) * 64 + lane] = pk(x1, y1);
        sx0 += x0 + x1; sx1 += y0 + y1;
        sq0 += x0 * x0 + x1 * x1; sq1 += y0 * y0 + y1 * y1;
    }

    __shared__ float ls[512], lq[512];
    ls[wav * 128 + lane * 2] = sx0;
    ls[wav * 128 + lane * 2 + 1] = sx1;
    lq[wav * 128 + lane * 2] = sq0;
    lq[wav * 128 + lane * 2 + 1] = sq1;
    __syncthreads();
    if (tid < 128) {
        float s = ls[tid] + ls[tid + 128] + ls[tid + 256] + ls[tid + 384];
        float q = lq[tid] + lq[tid + 128] + lq[tid + 256] + lq[tid + 384];
        atomAddG(&statOut[tid], s);
        atomAddG(&statOut[128 + tid], q);
    }
}

// ---------------- residual update: h += relu(bn(agg)); emit bf16 mirror ----------------
__global__ __launch_bounds__(256) void k_update(
    float* __restrict__ h, const u32* __restrict__ aggb,
    const float* __restrict__ bnSt, const float* __restrict__ bnG, const float* __restrict__ bnBe,
    u32* __restrict__ hb)
{
    __shared__ float sBN[256];
    int tid = threadIdx.x;
    if (tid < 128) {
        float s, f;
        bn_coef(bnSt, bnG, bnBe, tid, s, f);
        sBN[tid] = s;
        sBN[128 + tid] = f;
    }
    __syncthreads();

    int i = blockIdx.x * 256 + tid;
    int c0 = (i * 4) & 127;
    uint2 a = *(const uint2*)(aggb + (size_t)i * 2);
    float4 hv = *(float4*)(h + (size_t)i * 4);
    float4 sv = *(const float4*)(sBN + c0);
    float4 fv = *(const float4*)(sBN + 128 + c0);
    hv.x += fmaxf(0.f, bf_lo(a.x) * sv.x + fv.x);
    hv.y += fmaxf(0.f, bf_hi(a.x) * sv.y + fv.y);
    hv.z += fmaxf(0.f, bf_lo(a.y) * sv.z + fv.z);
    hv.w += fmaxf(0.f, bf_hi(a.y) * sv.w + fv.w);
    *(float4*)(h + (size_t)i * 4) = hv;
    *(uint2*)(hb + (size_t)i * 2) = make_uint2(pk(hv.x, hv.y), pk(hv.z, hv.w));
}

// ---------------- pooling with fused last-layer update (inline BN) ----------------
__global__ __launch_bounds__(256) void k_pool(
    const float* __restrict__ h, const u32* __restrict__ aggb,
    const float* __restrict__ bnSt, const float* __restrict__ bnG, const float* __restrict__ bnBe,
    const int* __restrict__ batch, float* __restrict__ hg)
{
    __shared__ float lsum[128];
    int tid = threadIdx.x;
    int c = tid & 127, half = tid >> 7;
    float sc, sf;
    bn_coef(bnSt, bnG, bnBe, c, sc, sf);
    int r0 = blockIdx.x * 64;
    int rend = min(r0 + 64, NN);
    int b0 = batch[r0], b1 = batch[rend - 1];

    if (b0 == b1) {
        float acc = 0.f;
        for (int r = r0 + half; r < rend; r += 2) {
            u32 a = aggb[(size_t)r * 64 + (c >> 1)];
            float av = (c & 1) ? bf_hi(a) : bf_lo(a);
            acc += h[(size_t)r * 128 + c] + fmaxf(0.f, av * sc + sf);
        }
        if (half) lsum[c] = acc;
        __syncthreads();
        if (!half) atomAddG(&hg[b0 * DD + c], acc + lsum[c]);
    } else {
        float acc = 0.f;
        int cur = batch[r0 + half];
        for (int r = r0 + half; r < rend; r += 2) {
            int b = batch[r];
            if (b != cur) { atomAddG(&hg[cur * DD + c], acc); acc = 0.f; cur = b; }
            u32 a = aggb[(size_t)r * 64 + (c >> 1)];
            float av = (c & 1) ? bf_hi(a) : bf_lo(a);
            acc += h[(size_t)r * 128 + c] + fmaxf(0.f, av * sc + sf);
        }
        atomAddG(&hg[cur * DD + c], acc);
    }
}

// ---------------- readout MLP ----------------
__global__ __launch_bounds__(128) void k_readout(
    const float* __restrict__ hg,
    const float* __restrict__ W1, const float* __restrict__ b1,
    const float* __restrict__ W2, const float* __restrict__ b2,
    const float* __restrict__ W3, const float* __restrict__ b3,
    float* __restrict__ out) {
    __shared__ float a0[128], a1[64], a2[32];
    int g = blockIdx.x, t = threadIdx.x;
    a0[t] = hg[g * DD + t];
    __syncthreads();
    if (t < 64) {
        float s = b1[t];
        for (int k = 0; k < 128; ++k) s += a0[k] * W1[k * 64 + t];
        a1[t] = fmaxf(s, 0.f);
    }
    __syncthreads();
    if (t < 32) {
        float s = b2[t];
        for (int k = 0; k < 64; ++k) s += a1[k] * W2[k * 32 + t];
        a2[t] = fmaxf(s, 0.f);
    }
    __syncthreads();
    if (t == 0) {
        float s = b3[0];
        for (int k = 0; k < 32; ++k) s += a2[k] * W3[k];
        out[g] = s;
    }
}

extern "C" void kernel_launch(void* const* d_in, const int* in_sizes, int n_in,
                              void* d_out, int out_size, void* d_ws, size_t ws_size,
                              hipStream_t stream) {
    const float* x      = (const float*)d_in[0];
    const int*   ei     = (const int*)d_in[1];
    const int*   batch  = (const int*)d_in[2];
    const float* enc_W1 = (const float*)d_in[3];
    const float* enc_g  = (const float*)d_in[5];
    const float* enc_be = (const float*)d_in[6];
    const float* enc_W2 = (const float*)d_in[7];
    const float* enc_b2 = (const float*)d_in[8];
    const float* conv_W = (const float*)d_in[9];
    // d_in[4]=enc_b1, d_in[10]=conv_b: dead (additive pre-BN bias cancels in BN)
    const float* bn_g   = (const float*)d_in[11];
    const float* bn_b   = (const float*)d_in[12];
    const float* ro_W1  = (const float*)d_in[13];
    const float* ro_b1  = (const float*)d_in[14];
    const float* ro_W2  = (const float*)d_in[15];
    const float* ro_b2  = (const float*)d_in[16];
    const float* ro_W3  = (const float*)d_in[17];
    const float* ro_b3  = (const float*)d_in[18];

    const int* srcI = ei;
    const int* dstI = ei + NE;

    float* ws   = (float*)d_ws;
    float* h    = ws;                          // [NN*DD] f32
    u32*   aggb = (u32*)(ws + 12800000);       // [NN*64] u32 — aliases encoder tb16
    u32*   hb   = (u32*)(ws + 19200000);       // [NN*64] u32 bf16 mirror of h
    u32*   t1b  = (u32*)(ws + 25600000);       // [NN][64] u32 row-major, pre-scaled
    u16*   wtb  = (u16*)(ws + 32000000);       // 5*16384 bf16
    float* dinv = ws + 32050000;               // [NN]
    float* stats= ws + 32150000;               // 4 blocks x 256 floats (sum|sq)
    float* hg   = ws + 32152000;               // [NG*DD]
    int*   offs = (int*)(ws + 32160000);       // [NN+1]
    int*   degI = (int*)(ws + 32270000);       // [NN]
    int*   bsum = (int*)(ws + 32370000);       // [512]
    u32*   eIdx = (u32*)(ws + 32380000);       // [NE] src indices

    u16* tb16 = (u16*)aggb;   // encoder tmp (bf16) aliases aggb
    float* stE = stats;        // encoder BN stats

    // ---- prep ----
    k_prepW<<<40, 256, 0, stream>>>(enc_W1, enc_W2, conv_W, wtb);
    hipMemsetAsync(stats, 0, 4 * 256 * sizeof(float), stream);

    // ---- CSR build ----
    hipMemsetAsync(degI, 0, NN * sizeof(int), stream);
    k_degI<<<2500, 256, 0, stream>>>(dstI, degI);
    k_scan1<<<391, 256, 0, stream>>>(degI, offs, bsum, dinv);
    k_scan2<<<1, 512, 0, stream>>>(bsum, 391);
    k_scan3<<<391, 256, 0, stream>>>(offs, bsum);
    hipMemsetAsync(degI, 0, NN * sizeof(int), stream);
    k_place<<<2500, 256, 0, stream>>>(srcI, dstI, offs, degI, eIdx);

    // ---- encoder: Linear -> BN -> ReLU -> Linear (BN inline in 2nd GEMM) ----
    k_mm<1><<<1563, 256, 0, stream>>>(x, wtb, nullptr, nullptr, nullptr, nullptr, nullptr,
                                      tb16, nullptr, stE);
    k_mm<2><<<1563, 256, 0, stream>>>(tb16, wtb + 16384, enc_b2, stE, enc_g, enc_be, nullptr,
                                      (u16*)hb, h, nullptr);

    // ---- GCN layers ----
    for (int l = 0; l < NL; ++l) {
        float* stL = stats + (size_t)(1 + l) * 256;
        k_mm<0><<<1563, 256, 0, stream>>>((const u16*)hb, wtb + (size_t)(2 + l) * 16384,
                                          nullptr, nullptr, nullptr, nullptr, dinv,
                                          (u16*)t1b, nullptr, nullptr);
        k_agg<<<6250, 256, 0, stream>>>(t1b, eIdx, offs, dinv, aggb, stL);
        if (l < NL - 1)
            k_update<<<12500, 256, 0, stream>>>(h, aggb, stL, bn_g + l * DD, bn_b + l * DD, hb);
    }

    // ---- pooling (fused last update, inline BN) + readout ----
    hipMemsetAsync(hg, 0, NG * DD * sizeof(float), stream);
    k_pool<<<1563, 256, 0, stream>>>(h, aggb, stats + 3 * 256, bn_g + 2 * DD, bn_b + 2 * DD, batch, hg);
    k_readout<<<NG, 128, 0, stream>>>(hg, ro_W1, ro_b1, ro_W2, ro_b2, ro_W3, ro_b3, (float*)d_out);
}

// Round 16
// 521.573 us; speedup vs baseline: 1.5280x; 1.5280x over previous
//
#include <hip/hip_runtime.h>
#include <hip/hip_bf16.h>

#define NN 100000
#define NE 640000
#define DD 128
#define NG 64
#define NL 3
#define BN_EPS 1e-5f

typedef unsigned short u16;
typedef unsigned int u32;
typedef __attribute__((ext_vector_type(8))) short short8;
typedef __attribute__((ext_vector_type(4))) float f32x4;

__device__ __forceinline__ void atomAddG(float* p, float v) { unsafeAtomicAdd(p, v); }

__device__ __forceinline__ float bf_lo(u32 u) { return __uint_as_float(u << 16); }
__device__ __forceinline__ float bf_hi(u32 u) { return __uint_as_float(u & 0xffff0000u); }
__device__ __forceinline__ float bfs(short s) { return __uint_as_float(((u32)(u16)s) << 16); }
__device__ __forceinline__ u16 bfb(float f) {
    __hip_bfloat16 b = __float2bfloat16(f);
    return *(u16*)&b;
}
__device__ __forceinline__ u32 pk(float a, float b) {
    return (u32)bfb(a) | ((u32)bfb(b) << 16);
}

// stat block layout: st[0..127] = column sums, st[128..255] = column sumsq
__device__ __forceinline__ void bn_coef(const float* __restrict__ st,
                                        const float* __restrict__ g,
                                        const float* __restrict__ be,
                                        int c, float& s, float& f) {
    float m = st[c] * (1.0f / NN);
    float v = st[128 + c] * (1.0f / NN) - m * m;
    s = g[c] * rsqrtf(v + BN_EPS);
    f = be[c] - m * s;
}

// ---------------- CSR build ----------------
__global__ void k_degI(const int* __restrict__ dst, int* __restrict__ degI) {
    int e = blockIdx.x * 256 + threadIdx.x;
    if (e < NE) atomicAdd(&degI[dst[e]], 1);
}

// scan1 + dinv fused
__global__ void k_scan1(const int* __restrict__ degI, int* __restrict__ offs, int* __restrict__ bsum,
                        float* __restrict__ dinv) {
    __shared__ int ls[256];
    int t = threadIdx.x;
    int i = blockIdx.x * 256 + t;
    int v = (i < NN) ? degI[i] : 0;
    if (i < NN) dinv[i] = v > 0 ? rsqrtf((float)v) : 0.f;
    ls[t] = v;
    __syncthreads();
    for (int off = 1; off < 256; off <<= 1) {
        int u = (t >= off) ? ls[t - off] : 0;
        __syncthreads();
        ls[t] += u;
        __syncthreads();
    }
    if (i < NN) offs[i] = ls[t] - v;
    if (t == 255) bsum[blockIdx.x] = ls[255];
}

__global__ void k_scan2(int* __restrict__ bsum, int nb) {
    __shared__ int ls[512];
    int t = threadIdx.x;
    int v = (t < nb) ? bsum[t] : 0;
    ls[t] = v;
    __syncthreads();
    for (int off = 1; off < 512; off <<= 1) {
        int u = (t >= off) ? ls[t - off] : 0;
        __syncthreads();
        ls[t] += u;
        __syncthreads();
    }
    if (t < nb) bsum[t] = ls[t] - v;
}

__global__ void k_scan3(int* __restrict__ offs, const int* __restrict__ bsum) {
    int i = blockIdx.x * 256 + threadIdx.x;
    if (i < NN) offs[i] += bsum[blockIdx.x];
    if (i == 0) offs[NN] = NE;
}

__global__ void k_place(const int* __restrict__ src, const int* __restrict__ dst,
                        const int* __restrict__ offs, int* __restrict__ cur,
                        u32* __restrict__ eIdx) {
    int e = blockIdx.x * 256 + threadIdx.x;
    if (e < NE) {
        int d = dst[e];
        int pos = offs[d] + atomicAdd(&cur[d], 1);
        eIdx[pos] = (u32)src[e];
    }
}

// W [k][n] f32 -> Wt [n][k] bf16 ; matrices: 0=enc_W1 1=enc_W2 2..4=conv_W
__global__ void k_prepW(const float* __restrict__ W1, const float* __restrict__ W2,
                        const float* __restrict__ CW, u16* __restrict__ wtb) {
    int m = blockIdx.x >> 3;
    const float* src = (m == 0) ? W1 : (m == 1) ? W2 : CW + (size_t)(m - 2) * 16384;
    u16* dst = wtb + (size_t)m * 16384;
    int base = (blockIdx.x & 7) * 2048 + threadIdx.x;
#pragma unroll
    for (int i = 0; i < 8; ++i) {
        int idx = base + i * 256;
        int k = idx >> 7, n = idx & 127;
        dst[n * 128 + k] = bfb(src[idx]);
    }
}

// ---------------- MFMA GEMM [NN,128] @ Wt[128][128] ----------------
// MODE 0: conv. A = hb (bf16). Out: t1 u32 row-major, rows PRE-SCALED by dinv[row].
// MODE 1: encoder1. A = x (f32, convert on load). Out: bf16 row-major + stats into statOut.
// MODE 2: encoder2. A = tb16 bf16; BN+ReLU coeffs computed INLINE from bnSt/bnG/bnBe;
//         +bias. Out: hb bf16 + h f32.
template <int MODE>
__global__ __launch_bounds__(256) void k_mm(
    const void* __restrict__ Av, const u16* __restrict__ Wt,
    const float* __restrict__ bias,
    const float* __restrict__ bnSt, const float* __restrict__ bnG, const float* __restrict__ bnBe,
    const float* __restrict__ dinv,
    u16* __restrict__ Cb, float* __restrict__ Cf,
    float* __restrict__ statOut)
{
    __shared__ float lC[64 * 128];
    __shared__ float sBN[256];
    int tid = threadIdx.x;
    int l = tid & 63, w = tid >> 6;
    int lr = l & 15, lg = l >> 4;
    int wcol = (w & 1) * 64, wrow = (w >> 1) * 32;

    if (MODE == 2) {
        if (tid < 128) {
            float s, f;
            bn_coef(bnSt, bnG, bnBe, tid, s, f);
            sBN[tid] = s;
            sBN[128 + tid] = f;
        }
        __syncthreads();
    }

    short8 Bf[4][4];
#pragma unroll
    for (int ct = 0; ct < 4; ++ct)
#pragma unroll
        for (int ks = 0; ks < 4; ++ks)
            Bf[ct][ks] = *(const short8*)(Wt + (size_t)(wcol + ct * 16 + lr) * 128 + ks * 32 + lg * 8);

    f32x4 acc[2][4];
#pragma unroll
    for (int rg = 0; rg < 2; ++rg)
#pragma unroll
        for (int ct = 0; ct < 4; ++ct)
            acc[rg][ct] = (f32x4){0.f, 0.f, 0.f, 0.f};

    int rbase = blockIdx.x * 64 + wrow;
#pragma unroll
    for (int rg = 0; rg < 2; ++rg) {
        int row = rbase + rg * 16 + lr;
        row = min(row, NN - 1);
        short8 Af[4];
        if (MODE == 1) {
            const float* af = (const float*)Av + (size_t)row * 128 + lg * 8;
#pragma unroll
            for (int ks = 0; ks < 4; ++ks) {
                float4 v0 = *(const float4*)(af + ks * 32);
                float4 v1 = *(const float4*)(af + ks * 32 + 4);
                short8 o;
                o[0] = (short)bfb(v0.x); o[1] = (short)bfb(v0.y);
                o[2] = (short)bfb(v0.z); o[3] = (short)bfb(v0.w);
                o[4] = (short)bfb(v1.x); o[5] = (short)bfb(v1.y);
                o[6] = (short)bfb(v1.z); o[7] = (short)bfb(v1.w);
                Af[ks] = o;
            }
        } else {
            const u16* ap = (const u16*)Av + (size_t)row * 128 + lg * 8;
#pragma unroll
            for (int ks = 0; ks < 4; ++ks) Af[ks] = *(const short8*)(ap + ks * 32);
            if (MODE == 2) {
#pragma unroll
                for (int ks = 0; ks < 4; ++ks) {
                    int cb = ks * 32 + lg * 8;
                    float4 s0 = *(const float4*)(sBN + cb), s1 = *(const float4*)(sBN + cb + 4);
                    float4 f0 = *(const float4*)(sBN + 128 + cb), f1 = *(const float4*)(sBN + 128 + cb + 4);
                    short8 a = Af[ks], o;
                    o[0] = (short)bfb(fmaxf(0.f, bfs(a[0]) * s0.x + f0.x));
                    o[1] = (short)bfb(fmaxf(0.f, bfs(a[1]) * s0.y + f0.y));
                    o[2] = (short)bfb(fmaxf(0.f, bfs(a[2]) * s0.z + f0.z));
                    o[3] = (short)bfb(fmaxf(0.f, bfs(a[3]) * s0.w + f0.w));
                    o[4] = (short)bfb(fmaxf(0.f, bfs(a[4]) * s1.x + f1.x));
                    o[5] = (short)bfb(fmaxf(0.f, bfs(a[5]) * s1.y + f1.y));
                    o[6] = (short)bfb(fmaxf(0.f, bfs(a[6]) * s1.z + f1.z));
                    o[7] = (short)bfb(fmaxf(0.f, bfs(a[7]) * s1.w + f1.w));
                    Af[ks] = o;
                }
            }
        }
#pragma unroll
        for (int ks = 0; ks < 4; ++ks)
#pragma unroll
            for (int ct = 0; ct < 4; ++ct)
                acc[rg][ct] = __builtin_amdgcn_mfma_f32_16x16x32_bf16(Af[ks], Bf[ct][ks], acc[rg][ct], 0, 0, 0);
    }

    if (MODE == 2) {
#pragma unroll
        for (int ct = 0; ct < 4; ++ct) {
            float bc = bias[wcol + ct * 16 + lr];
#pragma unroll
            for (int rg = 0; rg < 2; ++rg)
#pragma unroll
                for (int j = 0; j < 4; ++j) acc[rg][ct][j] += bc;
        }
    }

#pragma unroll
    for (int rg = 0; rg < 2; ++rg)
#pragma unroll
        for (int ct = 0; ct < 4; ++ct)
#pragma unroll
            for (int j = 0; j < 4; ++j)
                lC[(wrow + rg * 16 + lg * 4 + j) * 128 + wcol + ct * 16 + lr] = acc[rg][ct][j];
    __syncthreads();

    float cs[4] = {0.f, 0.f, 0.f, 0.f}, cq[4] = {0.f, 0.f, 0.f, 0.f};
#pragma unroll
    for (int i = 0; i < 8; ++i) {
        int eidx = i * 1024 + tid * 4;
        int lrow = eidx >> 7;
        int col = eidx & 127;
        int grow = blockIdx.x * 64 + lrow;
        if (grow < NN) {
            float4 v = *(float4*)(lC + eidx);
            if (MODE == 0) {
                float dd = dinv[grow];
                v.x *= dd; v.y *= dd; v.z *= dd; v.w *= dd;
                u32* Cs = (u32*)Cb;
                *(uint2*)(Cs + (size_t)grow * 64 + (col >> 1)) =
                    make_uint2(pk(v.x, v.y), pk(v.z, v.w));
            } else {
                uint2 o = make_uint2(pk(v.x, v.y), pk(v.z, v.w));
                *(uint2*)(Cb + (size_t)grow * 128 + col) = o;
                if (MODE == 2) *(float4*)(Cf + (size_t)grow * 128 + col) = v;
                if (MODE == 1) {
                    cs[0] += v.x; cs[1] += v.y; cs[2] += v.z; cs[3] += v.w;
                    cq[0] += v.x * v.x; cq[1] += v.y * v.y; cq[2] += v.z * v.z; cq[3] += v.w * v.w;
                }
            }
        }
    }

    if (MODE == 1) {
        __syncthreads();
        int g = tid >> 5, c0 = (tid & 31) * 4;
#pragma unroll
        for (int cc = 0; cc < 4; ++cc) {
            lC[g * 128 + c0 + cc] = cs[cc];
            lC[1024 + g * 128 + c0 + cc] = cq[cc];
        }
        __syncthreads();
        if (tid < 128) {
            float s = 0.f, q = 0.f;
#pragma unroll
            for (int g2 = 0; g2 < 8; ++g2) { s += lC[g2 * 128 + tid]; q += lC[1024 + g2 * 128 + tid]; }
            atomAddG(&statOut[tid], s);
            atomAddG(&statOut[128 + tid], q);
        }
    }
}

// ---------------- CSR pull aggregation (proven operating point): 2 dsts x chunk-8 ----------
__global__ __launch_bounds__(256) void k_agg(
    const u32* __restrict__ hwb,          // [NN][64] u32 (bf16x2), pre-scaled rows
    const u32* __restrict__ eIdx, const int* __restrict__ offs,
    const float* __restrict__ dinv,
    u32* __restrict__ aggb, float* __restrict__ statOut)
{
    int tid = threadIdx.x;
    int lane = tid & 63;
    int wav = tid >> 6;
    int gw = blockIdx.x * 4 + wav;
    int nw = gridDim.x * 4;
    float sx0 = 0.f, sx1 = 0.f, sq0 = 0.f, sq1 = 0.f;

    for (int d0 = gw * 2; d0 < NN; d0 += nw * 2) {
        int a0 = offs[d0], a1 = offs[d0 + 1], a2 = offs[d0 + 2];
        int len0 = a1 - a0, len1 = a2 - a1;
        int m0 = max(len0 - 1, 0), m1 = max(len1 - 1, 0);
        float x0 = 0.f, y0 = 0.f, x1 = 0.f, y1 = 0.f;
        int mx = max(len0, len1);
        for (int jb = 0; jb < mx; jb += 8) {
            u32 i0[8], i1[8];
#pragma unroll
            for (int q = 0; q < 8; ++q) {
                i0[q] = eIdx[min(a0 + min(jb + q, m0), NE - 1)];
                i1[q] = eIdx[min(a1 + min(jb + q, m1), NE - 1)];
            }
            u32 u0[8], u1[8];
#pragma unroll
            for (int q = 0; q < 8; ++q) {
                u0[q] = hwb[(size_t)i0[q] * 64 + lane];
                u1[q] = hwb[(size_t)i1[q] * 64 + lane];
            }
#pragma unroll
            for (int q = 0; q < 8; ++q) {
                bool v0 = (jb + q) < len0, v1 = (jb + q) < len1;
                x0 += v0 ? bf_lo(u0[q]) : 0.f;
                y0 += v0 ? bf_hi(u0[q]) : 0.f;
                x1 += v1 ? bf_lo(u1[q]) : 0.f;
                y1 += v1 ? bf_hi(u1[q]) : 0.f;
            }
        }
        float dd0 = dinv[d0], dd1 = dinv[d0 + 1];
        x0 *= dd0; y0 *= dd0; x1 *= dd1; y1 *= dd1;
        aggb[(size_t)d0 * 64 + lane] = pk(x0, y0);
        aggb[(size_t)(d0 + 1) * 64 + lane] = pk(x1, y1);
        sx0 += x0 + x1; sx1 += y0 + y1;
        sq0 += x0 * x0 + x1 * x1; sq1 += y0 * y0 + y1 * y1;
    }

    __shared__ float ls[512], lq[512];
    ls[wav * 128 + lane * 2] = sx0;
    ls[wav * 128 + lane * 2 + 1] = sx1;
    lq[wav * 128 + lane * 2] = sq0;
    lq[wav * 128 + lane * 2 + 1] = sq1;
    __syncthreads();
    if (tid < 128) {
        float s = ls[tid] + ls[tid + 128] + ls[tid + 256] + ls[tid + 384];
        float q = lq[tid] + lq[tid + 128] + lq[tid + 256] + lq[tid + 384];
        atomAddG(&statOut[tid], s);
        atomAddG(&statOut[128 + tid], q);
    }
}

// ---------------- residual update: h += relu(bn(agg)); emit bf16 mirror ----------------
__global__ __launch_bounds__(256) void k_update(
    float* __restrict__ h, const u32* __restrict__ aggb,
    const float* __restrict__ bnSt, const float* __restrict__ bnG, const float* __restrict__ bnBe,
    u32* __restrict__ hb)
{
    __shared__ float sBN[256];
    int tid = threadIdx.x;
    if (tid < 128) {
        float s, f;
        bn_coef(bnSt, bnG, bnBe, tid, s, f);
        sBN[tid] = s;
        sBN[128 + tid] = f;
    }
    __syncthreads();

    int i = blockIdx.x * 256 + tid;
    int c0 = (i * 4) & 127;
    uint2 a = *(const uint2*)(aggb + (size_t)i * 2);
    float4 hv = *(float4*)(h + (size_t)i * 4);
    float4 sv = *(const float4*)(sBN + c0);
    float4 fv = *(const float4*)(sBN + 128 + c0);
    hv.x += fmaxf(0.f, bf_lo(a.x) * sv.x + fv.x);
    hv.y += fmaxf(0.f, bf_hi(a.x) * sv.y + fv.y);
    hv.z += fmaxf(0.f, bf_lo(a.y) * sv.z + fv.z);
    hv.w += fmaxf(0.f, bf_hi(a.y) * sv.w + fv.w);
    *(float4*)(h + (size_t)i * 4) = hv;
    *(uint2*)(hb + (size_t)i * 2) = make_uint2(pk(hv.x, hv.y), pk(hv.z, hv.w));
}

// ---------------- pooling with fused last-layer update (inline BN) ----------------
__global__ __launch_bounds__(256) void k_pool(
    const float* __restrict__ h, const u32* __restrict__ aggb,
    const float* __restrict__ bnSt, const float* __restrict__ bnG, const float* __restrict__ bnBe,
    const int* __restrict__ batch, float* __restrict__ hg)
{
    __shared__ float lsum[128];
    int tid = threadIdx.x;
    int c = tid & 127, half = tid >> 7;
    float sc, sf;
    bn_coef(bnSt, bnG, bnBe, c, sc, sf);
    int r0 = blockIdx.x * 64;
    int rend = min(r0 + 64, NN);
    int b0 = batch[r0], b1 = batch[rend - 1];

    if (b0 == b1) {
        float acc = 0.f;
        for (int r = r0 + half; r < rend; r += 2) {
            u32 a = aggb[(size_t)r * 64 + (c >> 1)];
            float av = (c & 1) ? bf_hi(a) : bf_lo(a);
            acc += h[(size_t)r * 128 + c] + fmaxf(0.f, av * sc + sf);
        }
        if (half) lsum[c] = acc;
        __syncthreads();
        if (!half) atomAddG(&hg[b0 * DD + c], acc + lsum[c]);
    } else {
        float acc = 0.f;
        int cur = batch[r0 + half];
        for (int r = r0 + half; r < rend; r += 2) {
            int b = batch[r];
            if (b != cur) { atomAddG(&hg[cur * DD + c], acc); acc = 0.f; cur = b; }
            u32 a = aggb[(size_t)r * 64 + (c >> 1)];
            float av = (c & 1) ? bf_hi(a) : bf_lo(a);
            acc += h[(size_t)r * 128 + c] + fmaxf(0.f, av * sc + sf);
        }
        atomAddG(&hg[cur * DD + c], acc);
    }
}

// ---------------- readout MLP ----------------
__global__ __launch_bounds__(128) void k_readout(
    const float* __restrict__ hg,
    const float* __restrict__ W1, const float* __restrict__ b1,
    const float* __restrict__ W2, const float* __restrict__ b2,
    const float* __restrict__ W3, const float* __restrict__ b3,
    float* __restrict__ out) {
    __shared__ float a0[128], a1[64], a2[32];
    int g = blockIdx.x, t = threadIdx.x;
    a0[t] = hg[g * DD + t];
    __syncthreads();
    if (t < 64) {
        float s = b1[t];
        for (int k = 0; k < 128; ++k) s += a0[k] * W1[k * 64 + t];
        a1[t] = fmaxf(s, 0.f);
    }
    __syncthreads();
    if (t < 32) {
        float s = b2[t];
        for (int k = 0; k < 64; ++k) s += a1[k] * W2[k * 32 + t];
        a2[t] = fmaxf(s, 0.f);
    }
    __syncthreads();
    if (t == 0) {
        float s = b3[0];
        for (int k = 0; k < 32; ++k) s += a2[k] * W3[k];
        out[g] = s;
    }
}

extern "C" void kernel_launch(void* const* d_in, const int* in_sizes, int n_in,
                              void* d_out, int out_size, void* d_ws, size_t ws_size,
                              hipStream_t stream) {
    const float* x      = (const float*)d_in[0];
    const int*   ei     = (const int*)d_in[1];
    const int*   batch  = (const int*)d_in[2];
    const float* enc_W1 = (const float*)d_in[3];
    const float* enc_g  = (const float*)d_in[5];
    const float* enc_be = (const float*)d_in[6];
    const float* enc_W2 = (const float*)d_in[7];
    const float* enc_b2 = (const float*)d_in[8];
    const float* conv_W = (const float*)d_in[9];
    // d_in[4]=enc_b1, d_in[10]=conv_b: dead (additive pre-BN bias cancels in BN)
    const float* bn_g   = (const float*)d_in[11];
    const float* bn_b   = (const float*)d_in[12];
    const float* ro_W1  = (const float*)d_in[13];
    const float* ro_b1  = (const float*)d_in[14];
    const float* ro_W2  = (const float*)d_in[15];
    const float* ro_b2  = (const float*)d_in[16];
    const float* ro_W3  = (const float*)d_in[17];
    const float* ro_b3  = (const float*)d_in[18];

    const int* srcI = ei;
    const int* dstI = ei + NE;

    float* ws   = (float*)d_ws;
    float* h    = ws;                          // [NN*DD] f32
    u32*   aggb = (u32*)(ws + 12800000);       // [NN*64] u32 — aliases encoder tb16
    u32*   hb   = (u32*)(ws + 19200000);       // [NN*64] u32 bf16 mirror of h
    u32*   t1b  = (u32*)(ws + 25600000);       // [NN][64] u32 row-major, pre-scaled
    u16*   wtb  = (u16*)(ws + 32000000);       // 5*16384 bf16
    float* dinv = ws + 32050000;               // [NN]
    float* stats= ws + 32150000;               // 4 blocks x 256 floats (sum|sq)
    float* hg   = ws + 32152000;               // [NG*DD]
    int*   offs = (int*)(ws + 32160000);       // [NN+1]
    int*   degI = (int*)(ws + 32270000);       // [NN]
    int*   bsum = (int*)(ws + 32370000);       // [512]
    u32*   eIdx = (u32*)(ws + 32380000);       // [NE] src indices

    u16* tb16 = (u16*)aggb;   // encoder tmp (bf16) aliases aggb
    float* stE = stats;        // encoder BN stats

    // ---- prep ----
    k_prepW<<<40, 256, 0, stream>>>(enc_W1, enc_W2, conv_W, wtb);
    hipMemsetAsync(stats, 0, 4 * 256 * sizeof(float), stream);

    // ---- CSR build ----
    hipMemsetAsync(degI, 0, NN * sizeof(int), stream);
    k_degI<<<2500, 256, 0, stream>>>(dstI, degI);
    k_scan1<<<391, 256, 0, stream>>>(degI, offs, bsum, dinv);
    k_scan2<<<1, 512, 0, stream>>>(bsum, 391);
    k_scan3<<<391, 256, 0, stream>>>(offs, bsum);
    hipMemsetAsync(degI, 0, NN * sizeof(int), stream);
    k_place<<<2500, 256, 0, stream>>>(srcI, dstI, offs, degI, eIdx);

    // ---- encoder: Linear -> BN -> ReLU -> Linear (BN inline in 2nd GEMM) ----
    k_mm<1><<<1563, 256, 0, stream>>>(x, wtb, nullptr, nullptr, nullptr, nullptr, nullptr,
                                      tb16, nullptr, stE);
    k_mm<2><<<1563, 256, 0, stream>>>(tb16, wtb + 16384, enc_b2, stE, enc_g, enc_be, nullptr,
                                      (u16*)hb, h, nullptr);

    // ---- GCN layers ----
    for (int l = 0; l < NL; ++l) {
        float* stL = stats + (size_t)(1 + l) * 256;
        k_mm<0><<<1563, 256, 0, stream>>>((const u16*)hb, wtb + (size_t)(2 + l) * 16384,
                                          nullptr, nullptr, nullptr, nullptr, dinv,
                                          (u16*)t1b, nullptr, nullptr);
        k_agg<<<2048, 256, 0, stream>>>(t1b, eIdx, offs, dinv, aggb, stL);
        if (l < NL - 1)
            k_update<<<12500, 256, 0, stream>>>(h, aggb, stL, bn_g + l * DD, bn_b + l * DD, hb);
    }

    // ---- pooling (fused last update, inline BN) + readout ----
    hipMemsetAsync(hg, 0, NG * DD * sizeof(float), stream);
    k_pool<<<1563, 256, 0, stream>>>(h, aggb, stats + 3 * 256, bn_g + 2 * DD, bn_b + 2 * DD, batch, hg);
    k_readout<<<NG, 128, 0, stream>>>(hg, ro_W1, ro_b1, ro_W2, ro_b2, ro_W3, ro_b3, (float*)d_out);
}